// Round 15
// baseline (150.938 us; speedup 1.0000x reference)
//
#include <hip/hip_runtime.h>
#include <math.h>

// NUFFT roundtrip on bf16 MFMA (16x16x32), fp32 accumulate.
// R15 = R12 (proven best, 132us) with ONE change: fwd wave-tile 32x64 -> 64x64
//   (block 64y x 256m, 4 waves, BK=64, 80KB dynamic LDS single-buffered).
//   Per K-step/wave: 64 MFMA (310cy) vs 16 ds_read_b128 (192cy) -> MFMA-dominant
//   (R12 was 32 vs 12 = LDS co-bound at MfmaUtil 26%). Epilogue loses redbuf:
//   each wave owns all 64 y of its 64 m -> in-wave shfl reduce only.
// R14 LESSON: 2-phase dbuf hurts BOTH kernels here (occupancy halves; cross-block
//   overlap at 4 blocks/CU beats intra-block pipelining). adj = R12 single-buffered.

#define NN      320
#define BCC     8
#define MREAL   6008
#define MSTR    6144
#define P1STR   6016
#define SKADJ   8
#define CHUNKM  (MSTR / SKADJ)      // 768
#define NADJB   (SKADJ * BCC * 25)  // 1600
#define TWOPI   6.283185307179586f

typedef __attribute__((ext_vector_type(8))) short short8_t;
typedef __attribute__((ext_vector_type(4))) float float4_t;

__device__ __forceinline__ unsigned short f2bf(float f) {
    union { float f; unsigned u; } v; v.f = f;
    unsigned r = v.u + 0x7fff + ((v.u >> 16) & 1);
    return (unsigned short)(r >> 16);
}
__device__ __forceinline__ float bf2f(unsigned short h) {
    union { unsigned u; float f; } v; v.u = ((unsigned)h) << 16;
    return v.f;
}
__device__ __forceinline__ short8_t neg8(short8_t v) {
    short8_t r;
    #pragma unroll
    for (int i = 0; i < 8; ++i) r[i] = v[i] ^ (short)0x8000;
    return r;
}
__device__ __forceinline__ float gval(int i) { return (float)(i - NN/2); }

__device__ __forceinline__ void phase_cs(float k, float g, float* c, float* s) {
    float rev = k * (g * (1.0f / (float)NN));
    rev -= rintf(rev);
    float th = rev * TWOPI;
    __sincosf(th, s, c);
}

// async global -> LDS, 16B/lane, offset 0 (R11 lesson: imm offset moves LDS dest too)
__device__ __forceinline__ void gld16(const unsigned short* g, unsigned short* l) {
    __builtin_amdgcn_global_load_lds(
        (const __attribute__((address_space(1))) unsigned int*)g,
        (__attribute__((address_space(3))) unsigned int*)l, 16, 0, 0);
}

// ============ gen_A: Ax_sw[m][x], AxT_sw[x][m], AyT plain [y][m] ============
__global__ __launch_bounds__(256) void gen_A(
    const float* __restrict__ traj,
    unsigned short* __restrict__ Ax_r, unsigned short* __restrict__ Ax_i,
    unsigned short* __restrict__ AxT_r, unsigned short* __restrict__ AxT_i,
    unsigned short* __restrict__ AyT_r, unsigned short* __restrict__ AyT_i)
{
    __shared__ __align__(16) float lc[64][65];
    __shared__ __align__(16) float ls[64][65];
    __shared__ float kxv[64], kyv[64];
    const int tid = threadIdx.x;
    const int m0 = blockIdx.x * 64;
    const int g0 = blockIdx.y * 64;

    if (tid < 64) {
        int m = m0 + tid;
        kxv[tid] = (m < MREAL) ? traj[2*m]     : 0.f;
        kyv[tid] = (m < MREAL) ? traj[2*m + 1] : 0.f;
    }
    __syncthreads();

    #pragma unroll
    for (int it = 0; it < 16; ++it) {
        int e = tid + it * 256;
        int mi = e >> 6, gi = e & 63;
        float c, s;
        phase_cs(kxv[mi], gval(g0 + gi), &c, &s);
        bool valid = (m0 + mi) < MREAL;
        lc[mi][gi] = valid ? c : 0.f;
        ls[mi][gi] = valid ? s : 0.f;
    }
    __syncthreads();
    #pragma unroll
    for (int it = 0; it < 16; ++it) {   // Ax_sw[m][x0 + (xi ^ ((m&7)<<3))] = (c,-s)
        int e = tid + it * 256;
        int mi = e >> 6, xi = e & 63;
        int m = m0 + mi;
        size_t o = (size_t)m * NN + g0 + (xi ^ ((m & 7) << 3));
        Ax_r[o] = f2bf(lc[mi][xi]);
        Ax_i[o] = f2bf(-ls[mi][xi]);
    }
    #pragma unroll
    for (int it = 0; it < 16; ++it) {   // AxT_sw[x][m0 + (mi ^ ((x&7)<<3))] = (c,+s)
        int e = tid + it * 256;
        int xi = e >> 6, mi = e & 63;
        int x = g0 + xi;
        size_t o = (size_t)x * MSTR + m0 + (mi ^ ((x & 7) << 3));
        AxT_r[o] = f2bf(lc[mi][xi]);
        AxT_i[o] = f2bf(ls[mi][xi]);
    }
    __syncthreads();

    #pragma unroll
    for (int it = 0; it < 16; ++it) {
        int e = tid + it * 256;
        int mi = e >> 6, gi = e & 63;
        float c, s;
        phase_cs(kyv[mi], gval(g0 + gi), &c, &s);
        bool valid = (m0 + mi) < MREAL;
        lc[mi][gi] = valid ? c : 0.f;
        ls[mi][gi] = valid ? s : 0.f;
    }
    __syncthreads();
    #pragma unroll
    for (int it = 0; it < 16; ++it) {   // AyT[y][m] plain = (c,+s) = conj(Ay)
        int e = tid + it * 256;
        int yi = e >> 6, mi = e & 63;
        size_t o = (size_t)(g0 + yi) * MSTR + (m0 + mi);
        AyT_r[o] = f2bf(lc[mi][yi]);
        AyT_i[o] = f2bf(ls[mi][yi]);
    }
}

// ============ conv_img: inp float2 [bc][x][y] -> iT_sw bf16 [bc][y][x swz] ============
__global__ __launch_bounds__(256) void conv_img(
    const float* __restrict__ inp,
    unsigned short* __restrict__ iT_r, unsigned short* __restrict__ iT_i)
{
    __shared__ __align__(16) float2 t[64][65];
    const int tid = threadIdx.x;
    const int x0 = blockIdx.x * 64, y0 = blockIdx.y * 64, bc = blockIdx.z;
    const float2* ip = (const float2*)inp;
    #pragma unroll
    for (int it = 0; it < 16; ++it) {
        int e = tid + it * 256;
        int r = e >> 6, c = e & 63;
        t[r][c] = ip[((size_t)bc * NN + (x0 + r)) * NN + (y0 + c)];
    }
    __syncthreads();
    #pragma unroll
    for (int it = 0; it < 16; ++it) {
        int e = tid + it * 256;
        int yy = e >> 6, xx = e & 63;
        float2 v = t[xx][yy];
        int y = y0 + yy;
        size_t o = ((size_t)bc * NN + y) * NN + x0 + (xx ^ ((y & 7) << 3));
        iT_r[o] = f2bf(v.x);
        iT_i[o] = f2bf(v.y);
    }
}

// ============ fwd_gemm: 64y x 256m, wave-tile 64x64, BK=64, 80KB dyn LDS ============
// LDS (ushort): Ar[0,4K) 64x64, Ai[4K,8K), Br[8K,24K) 256x64, Bi[24K,40K).
__global__ __launch_bounds__(256) void fwd_gemm(
    const unsigned short* __restrict__ iT_r, const unsigned short* __restrict__ iT_i,
    const unsigned short* __restrict__ Ax_r, const unsigned short* __restrict__ Ax_i,
    const unsigned short* __restrict__ AyT_r, const unsigned short* __restrict__ AyT_i,
    float2* __restrict__ partial1)
{
    extern __shared__ __align__(16) unsigned short ST[];   // 40960 ushorts = 80KB

    const int tid = threadIdx.x;
    const int bid = blockIdx.x;
    const int nid = (bid & 7) * 120 + (bid >> 3);   // grid 960 = 24mt*5yt*8bc
    const int mt  = nid / 40;
    const int r40 = nid - mt * 40;
    const int yt  = r40 % 5;
    const int bc  = r40 / 5;
    const int m0  = mt * 256;
    const int y0  = yt * 64;

    float4_t accR[4][4], accI[4][4];
    #pragma unroll
    for (int i = 0; i < 4; ++i)
        #pragma unroll
        for (int j = 0; j < 4; ++j) { accR[i][j] = (float4_t)0.f; accI[i][j] = (float4_t)0.f; }

    const int lane = tid & 63, wid = tid >> 6;     // wave owns m-column wid*64
    const int ar = lane & 15, kb = lane >> 4;
    const int sxor = (lane & 7) << 3;

    const int lrow = lane >> 3;
    const int cb8  = (lane & 7) * 8;

    // staging addresses computed ONCE (20 issues/wave; segs: A_r 0-7, A_i 8-15,
    // B_r 16-47, B_i 48-79; seg s holds 8 rows starting at (s-section)*8)
    const unsigned short* gp[20];
    unsigned short* lp[20];
    #pragma unroll
    for (int j = 0; j < 20; ++j) {
        int s = wid + 4 * j;
        const unsigned short* g;
        if (s < 16) {                          // A: iT_sw rows y0..y0+63
            int row = (s & 7) * 8 + lrow;
            const unsigned short* pl = (s < 8) ? iT_r : iT_i;
            g = pl + ((size_t)bc * NN + (y0 + row)) * NN + cb8;
        } else {                               // B: Ax_sw rows m0..m0+255
            int row = ((s - 16) & 31) * 8 + lrow;
            const unsigned short* pl = (s < 48) ? Ax_r : Ax_i;
            g = pl + (size_t)(m0 + row) * NN + cb8;
        }
        gp[j] = g;
        lp[j] = &ST[s * 512];
    }

    for (int t = 0; t < 5; ++t) {              // NN/64 x-tiles
        #pragma unroll
        for (int j = 0; j < 20; ++j) gld16(gp[j], lp[j]);
        #pragma unroll
        for (int j = 0; j < 20; ++j) gp[j] += 64;
        __syncthreads();                       // vmcnt drain -> tiles ready

        #pragma unroll
        for (int ks = 0; ks < 2; ++ks) {
            const int e = (ks * 32 + kb * 8) ^ sxor;
            short8_t a_r[4], a_i[4], a_n[4], b_r[4], b_i[4];
            #pragma unroll
            for (int iy = 0; iy < 4; ++iy) {
                int rr = iy * 16 + ar;
                a_r[iy] = *(const short8_t*)&ST[rr * 64 + e];
                a_i[iy] = *(const short8_t*)&ST[4096 + rr * 64 + e];
                a_n[iy] = neg8(a_i[iy]);
            }
            #pragma unroll
            for (int jm = 0; jm < 4; ++jm) {
                int cc = wid * 64 + jm * 16 + ar;
                b_r[jm] = *(const short8_t*)&ST[8192  + cc * 64 + e];
                b_i[jm] = *(const short8_t*)&ST[24576 + cc * 64 + e];
            }
            #pragma unroll
            for (int iy = 0; iy < 4; ++iy)
                #pragma unroll
                for (int jm = 0; jm < 4; ++jm) {
                    accR[iy][jm] = __builtin_amdgcn_mfma_f32_16x16x32_bf16(a_r[iy], b_r[jm], accR[iy][jm], 0, 0, 0);
                    accR[iy][jm] = __builtin_amdgcn_mfma_f32_16x16x32_bf16(a_n[iy], b_i[jm], accR[iy][jm], 0, 0, 0);
                    accI[iy][jm] = __builtin_amdgcn_mfma_f32_16x16x32_bf16(a_r[iy], b_i[jm], accI[iy][jm], 0, 0, 0);
                    accI[iy][jm] = __builtin_amdgcn_mfma_f32_16x16x32_bf16(a_i[iy], b_r[jm], accI[iy][jm], 0, 0, 0);
                }
        }
        __syncthreads();
    }

    // epilogue: ksp partial = sum_y D[y][m]*Ay[m][y]; each wave owns ALL 64 y of
    // its 64 m -> in-wave shfl reduce across kb groups, lanes 0-15 write.
    #pragma unroll
    for (int jm = 0; jm < 4; ++jm) {
        float sr = 0.f, si = 0.f;
        int m = m0 + wid * 64 + jm * 16 + ar;
        #pragma unroll
        for (int iy = 0; iy < 4; ++iy)
            #pragma unroll
            for (int q = 0; q < 4; ++q) {
                int y = y0 + iy * 16 + kb * 4 + q;
                float c  = bf2f(AyT_r[(size_t)y * MSTR + m]);
                float sy = bf2f(AyT_i[(size_t)y * MSTR + m]);
                float Tr = accR[iy][jm][q], Ti = accI[iy][jm][q];
                sr += Tr * c + Ti * sy;
                si += Ti * c - Tr * sy;
            }
        sr += __shfl_xor(sr, 16); sr += __shfl_xor(sr, 32);
        si += __shfl_xor(si, 16); si += __shfl_xor(si, 32);
        if ((lane & 48) == 0 && m < MREAL)
            partial1[((size_t)bc * 5 + yt) * P1STR + m] = make_float2(sr, si);
    }
}

// ============ reduce_ksp ============
__global__ void reduce_ksp(const float2* __restrict__ partial1,
                           float2* __restrict__ ksp)
{
    int mp = blockIdx.x * 256 + threadIdx.x;   // grid (24, 8)
    int bc = blockIdx.y;
    float2 r = make_float2(0.f, 0.f);
    if (mp < MREAL) {
        #pragma unroll
        for (int yt = 0; yt < 5; ++yt) {
            float2 v = partial1[((size_t)bc * 5 + yt) * P1STR + mp];
            r.x += v.x; r.y += v.y;
        }
    }
    ksp[(size_t)bc * MSTR + mp] = r;
}

// ============ gen_U: U_sw[bc][y][m ^ ((y&7)<<3)] = ksp[m]*conjAy[m][y] ============
__global__ __launch_bounds__(256) void gen_U(
    const unsigned short* __restrict__ AyT_r, const unsigned short* __restrict__ AyT_i,
    const float2* __restrict__ ksp,
    unsigned short* __restrict__ U_r, unsigned short* __restrict__ U_i)
{
    const int tid = threadIdx.x;
    const int m0 = blockIdx.x * 2048 + tid * 8;   // grid.x = 3
    const int y  = blockIdx.y;
    const int bc = blockIdx.z;

    short8_t yr = *(const short8_t*)(AyT_r + (size_t)y * MSTR + m0);
    short8_t yi = *(const short8_t*)(AyT_i + (size_t)y * MSTR + m0);
    const float2* kp = ksp + (size_t)bc * MSTR + m0;
    short8_t ur, ui;
    #pragma unroll
    for (int j = 0; j < 8; ++j) {
        float2 k = kp[j];
        float cr = bf2f((unsigned short)yr[j]);
        float ci = bf2f((unsigned short)yi[j]);
        ur[j] = (short)f2bf(k.x * cr - k.y * ci);
        ui[j] = (short)f2bf(k.x * ci + k.y * cr);
    }
    size_t o = ((size_t)bc * NN + y) * MSTR + (m0 ^ ((y & 7) << 3));
    *(short8_t*)(U_r + o) = ur;
    *(short8_t*)(U_i + o) = ui;
}

// ---- adj compute body (LDS: Ar[0,4K) Ai[4K,8K) Br[8K,12K) Bi[12K,16K))
__device__ __forceinline__ void acompute(
    const unsigned short* ST, float4_t (&accR)[2][2], float4_t (&accI)[2][2],
    int kb, int sxor, int wx, int wyy, int ar)
{
    #pragma unroll
    for (int ks = 0; ks < 2; ++ks) {
        const int e = (ks * 32 + kb * 8) ^ sxor;
        short8_t a_r[2], a_i[2], a_n[2], b_r[2], b_i[2];
        #pragma unroll
        for (int ix = 0; ix < 2; ++ix) {
            int rr = wx * 32 + ix * 16 + ar;
            a_r[ix] = *(const short8_t*)&ST[rr * 64 + e];
            a_i[ix] = *(const short8_t*)&ST[4096 + rr * 64 + e];
            a_n[ix] = neg8(a_i[ix]);
        }
        #pragma unroll
        for (int jy = 0; jy < 2; ++jy) {
            int cc = wyy * 32 + jy * 16 + ar;
            b_r[jy] = *(const short8_t*)&ST[8192  + cc * 64 + e];
            b_i[jy] = *(const short8_t*)&ST[12288 + cc * 64 + e];
        }
        #pragma unroll
        for (int ix = 0; ix < 2; ++ix)
            #pragma unroll
            for (int jy = 0; jy < 2; ++jy) {
                accR[ix][jy] = __builtin_amdgcn_mfma_f32_16x16x32_bf16(a_r[ix], b_r[jy], accR[ix][jy], 0, 0, 0);
                accR[ix][jy] = __builtin_amdgcn_mfma_f32_16x16x32_bf16(a_n[ix], b_i[jy], accR[ix][jy], 0, 0, 0);
                accI[ix][jy] = __builtin_amdgcn_mfma_f32_16x16x32_bf16(a_r[ix], b_i[jy], accI[ix][jy], 0, 0, 0);
                accI[ix][jy] = __builtin_amdgcn_mfma_f32_16x16x32_bf16(a_i[ix], b_r[jy], accI[ix][jy], 0, 0, 0);
            }
    }
}

// ===== adj_gemm_pre: 64x x 64y, BK=64, split-K=8, single-buffered (R12) =====
template<int FP32P>
__global__ __launch_bounds__(256) void adj_gemm_pre(
    const unsigned short* __restrict__ AxT_r, const unsigned short* __restrict__ AxT_i,
    const unsigned short* __restrict__ U_r, const unsigned short* __restrict__ U_i,
    void* __restrict__ partial2)
{
    __shared__ __align__(16) unsigned short ST[16384];

    const int tid = threadIdx.x;
    const int bid = blockIdx.x;
    const int nid = (bid & 7) * (NADJB / 8) + (bid >> 3);
    const int bcsk = nid / 25;
    const int xy = nid - bcsk * 25;
    const int xt = xy / 5, yt = xy % 5;
    const int bc = bcsk % BCC, sk = bcsk / BCC;
    const int x0 = xt * 64, y0 = yt * 64;
    const int kbeg = sk * CHUNKM;

    float4_t accR[2][2], accI[2][2];
    #pragma unroll
    for (int i = 0; i < 2; ++i)
        #pragma unroll
        for (int j = 0; j < 2; ++j) { accR[i][j] = (float4_t)0.f; accI[i][j] = (float4_t)0.f; }

    const int lane = tid & 63, wid = tid >> 6;
    const int wx = wid >> 1, wyy = wid & 1;
    const int ar = lane & 15, kb = lane >> 4;
    const int sxor = (lane & 7) << 3;

    const int lrow = lane >> 3;
    const int cb8  = (lane & 7) * 8;

    // staging addresses computed ONCE (8 issues/wave)
    const unsigned short* gp[8];
    unsigned short* lp[8];
    #pragma unroll
    for (int j = 0; j < 8; ++j) {
        int s = wid + 4 * j;                   // 0..31
        int row = (s & 7) * 8 + lrow;          // 0..63
        const unsigned short* g;
        if (s < 16) {                          // A: AxT_sw rows x0..x0+63
            const unsigned short* pl = (s < 8) ? AxT_r : AxT_i;
            g = pl + (size_t)(x0 + row) * MSTR + kbeg + cb8;
        } else {                               // B: U_sw rows y0..y0+63
            const unsigned short* pl = (s < 24) ? U_r : U_i;
            g = pl + ((size_t)bc * NN + (y0 + row)) * MSTR + kbeg + cb8;
        }
        gp[j] = g;
        lp[j] = &ST[s * 512];
    }

    for (int t = 0; t < CHUNKM / 64; ++t) {    // 12 m-tiles
        #pragma unroll
        for (int j = 0; j < 8; ++j) gld16(gp[j], lp[j]);
        #pragma unroll
        for (int j = 0; j < 8; ++j) gp[j] += 64;
        __syncthreads();
        acompute(&ST[0], accR, accI, kb, sxor, wx, wyy, ar);
        __syncthreads();
    }

    #pragma unroll
    for (int ix = 0; ix < 2; ++ix)
        #pragma unroll
        for (int jy = 0; jy < 2; ++jy)
            #pragma unroll
            for (int q = 0; q < 4; ++q) {
                int x = x0 + wx * 32 + ix * 16 + kb * 4 + q;
                int y = y0 + wyy * 32 + jy * 16 + ar;
                size_t o = (((size_t)sk * BCC + bc) * NN + x) * NN + y;
                float vr = accR[ix][jy][q], vi = accI[ix][jy][q];
                if (FP32P) {
                    ((float2*)partial2)[o] = make_float2(vr, vi);
                } else {
                    ((unsigned*)partial2)[o] =
                        (unsigned)f2bf(vr) | ((unsigned)f2bf(vi) << 16);
                }
            }
}

// ============ adj_gemm_fb: fallback (no U precompute, fused scale) ============
template<int FP32P>
__global__ __launch_bounds__(256) void adj_gemm_fb(
    const unsigned short* __restrict__ AxT_r, const unsigned short* __restrict__ AxT_i,
    const unsigned short* __restrict__ AyT_r, const unsigned short* __restrict__ AyT_i,
    const float2* __restrict__ ksp, void* __restrict__ partial2)
{
    __shared__ __align__(16) unsigned short Ar[64][72], Ai[64][72];
    __shared__ __align__(16) unsigned short Br[64][72], Bi[64][72];
    __shared__ __align__(16) float2 kspl[CHUNKM];

    const int tid = threadIdx.x;
    const int bid = blockIdx.x;
    const int nid = (bid & 7) * (NADJB / 8) + (bid >> 3);
    const int bcsk = nid / 25;
    const int xy = nid - bcsk * 25;
    const int xt = xy / 5, yt = xy % 5;
    const int bc = bcsk % BCC, sk = bcsk / BCC;
    const int x0 = xt * 64, y0 = yt * 64;
    const int kbeg = sk * CHUNKM;

    #pragma unroll
    for (int it = 0; it < CHUNKM / 256; ++it)
        kspl[tid + it * 256] = ksp[(size_t)bc * MSTR + kbeg + tid + it * 256];
    __syncthreads();

    float4_t accR[2][2], accI[2][2];
    #pragma unroll
    for (int i = 0; i < 2; ++i)
        #pragma unroll
        for (int j = 0; j < 2; ++j) { accR[i][j] = (float4_t)0.f; accI[i][j] = (float4_t)0.f; }

    const int lane = tid & 63, wid = tid >> 6;
    const int wx = wid >> 1, wyy = wid & 1;
    const int ar = lane & 15, kb = lane >> 4;
    const int sxor = (lane & 7) << 3;

    for (int mk = 0; mk < CHUNKM; mk += 64) {
        #pragma unroll
        for (int it = 0; it < 2; ++it) {
            int e = tid + it * 256;
            int row = e >> 3, gr = e & 7;
            size_t o = (size_t)(x0 + row) * MSTR + kbeg + mk + gr * 8;
            *(short8_t*)&Ar[row][gr * 8] = *(const short8_t*)(AxT_r + o);
            *(short8_t*)&Ai[row][gr * 8] = *(const short8_t*)(AxT_i + o);
        }
        #pragma unroll
        for (int it = 0; it < 2; ++it) {
            int e = tid + it * 256;
            int row = e >> 3, gr = e & 7;
            size_t o = (size_t)(y0 + row) * MSTR + kbeg + mk + gr * 8;
            short8_t yr = *(const short8_t*)(AyT_r + o);
            short8_t yi = *(const short8_t*)(AyT_i + o);
            short8_t br, bi2;
            #pragma unroll
            for (int j = 0; j < 8; ++j) {
                float2 k = kspl[mk + gr * 8 + j];
                float cr = bf2f((unsigned short)yr[j]);
                float ci = bf2f((unsigned short)yi[j]);
                br[j]  = (short)f2bf(k.x * cr - k.y * ci);
                bi2[j] = (short)f2bf(k.x * ci + k.y * cr);
            }
            *(short8_t*)&Br[row][gr * 8] = br;
            *(short8_t*)&Bi[row][gr * 8] = bi2;
        }
        __syncthreads();

        #pragma unroll
        for (int ks = 0; ks < 2; ++ks) {
            const int ea = (ks * 32 + kb * 8) ^ sxor;   // A content block-swizzled
            const int eb = ks * 32 + kb * 8;            // B staged plain
            short8_t a_r[2], a_i[2], a_n[2], b_r[2], b_i[2];
            #pragma unroll
            for (int ix = 0; ix < 2; ++ix) {
                int rr = wx * 32 + ix * 16 + ar;
                a_r[ix] = *(const short8_t*)&Ar[rr][ea];
                a_i[ix] = *(const short8_t*)&Ai[rr][ea];
                a_n[ix] = neg8(a_i[ix]);
            }
            #pragma unroll
            for (int jy = 0; jy < 2; ++jy) {
                int cc = wyy * 32 + jy * 16 + ar;
                b_r[jy] = *(const short8_t*)&Br[cc][eb];
                b_i[jy] = *(const short8_t*)&Bi[cc][eb];
            }
            #pragma unroll
            for (int ix = 0; ix < 2; ++ix)
                #pragma unroll
                for (int jy = 0; jy < 2; ++jy) {
                    accR[ix][jy] = __builtin_amdgcn_mfma_f32_16x16x32_bf16(a_r[ix], b_r[jy], accR[ix][jy], 0, 0, 0);
                    accR[ix][jy] = __builtin_amdgcn_mfma_f32_16x16x32_bf16(a_n[ix], b_i[jy], accR[ix][jy], 0, 0, 0);
                    accI[ix][jy] = __builtin_amdgcn_mfma_f32_16x16x32_bf16(a_r[ix], b_i[jy], accI[ix][jy], 0, 0, 0);
                    accI[ix][jy] = __builtin_amdgcn_mfma_f32_16x16x32_bf16(a_i[ix], b_r[jy], accI[ix][jy], 0, 0, 0);
                }
        }
        __syncthreads();
    }

    #pragma unroll
    for (int ix = 0; ix < 2; ++ix)
        #pragma unroll
        for (int jy = 0; jy < 2; ++jy)
            #pragma unroll
            for (int q = 0; q < 4; ++q) {
                int x = x0 + wx * 32 + ix * 16 + kb * 4 + q;
                int y = y0 + wyy * 32 + jy * 16 + ar;
                size_t o = (((size_t)sk * BCC + bc) * NN + x) * NN + y;
                float vr = accR[ix][jy][q], vi = accI[ix][jy][q];
                if (FP32P) {
                    ((float2*)partial2)[o] = make_float2(vr, vi);
                } else {
                    ((unsigned*)partial2)[o] =
                        (unsigned)f2bf(vr) | ((unsigned)f2bf(vi) << 16);
                }
            }
}

// ============ reduce_out ============
template<int FP32P>
__global__ void reduce_out(const void* __restrict__ partial2,
                           float2* __restrict__ out)
{
    size_t total = (size_t)BCC * NN * NN;
    size_t idx = (size_t)blockIdx.x * 256 + threadIdx.x;
    if (idx >= total) return;
    float2 r = make_float2(0.f, 0.f);
    #pragma unroll
    for (int s = 0; s < SKADJ; ++s) {
        if (FP32P) {
            float2 v = ((const float2*)partial2)[s * total + idx];
            r.x += v.x; r.y += v.y;
        } else {
            unsigned u = ((const unsigned*)partial2)[s * total + idx];
            r.x += bf2f((unsigned short)(u & 0xffff));
            r.y += bf2f((unsigned short)(u >> 16));
        }
    }
    out[idx] = r;
}

// ============ host ============
extern "C" void kernel_launch(void* const* d_in, const int* in_sizes, int n_in,
                              void* d_out, int out_size, void* d_ws, size_t ws_size,
                              hipStream_t stream)
{
    const float* inp  = (const float*)d_in[0];
    const float* traj = (const float*)d_in[1];

    char* ws = (char*)d_ws;
    const size_t PL = (size_t)NN * MSTR * 2;           // 3,932,160 B per bf16 plane
    unsigned short* AxT_r = (unsigned short*)(ws);
    unsigned short* AxT_i = (unsigned short*)(ws + PL);
    unsigned short* AyT_r = (unsigned short*)(ws + 2 * PL);
    unsigned short* AyT_i = (unsigned short*)(ws + 3 * PL);
    float2* ksp = (float2*)(ws + 4 * PL);
    const size_t KSPB = (size_t)BCC * MSTR * 8;        // 393,216
    const size_t BASE = 4 * PL + KSPB;                 // 16,121,856
    char* rb = ws + BASE;
    // fwd phase (dead after reduce_ksp; U / adj partials alias it):
    unsigned short* Ax_r = (unsigned short*)(rb);
    unsigned short* Ax_i = (unsigned short*)(rb + PL);
    const size_t ITP = (size_t)BCC * NN * NN * 2;      // 1,638,400 per plane
    unsigned short* iT_r = (unsigned short*)(rb + 2 * PL);
    unsigned short* iT_i = (unsigned short*)(rb + 2 * PL + ITP);
    float2* partial1 = (float2*)(rb + 2 * PL + 2 * ITP);
    // adj phase:
    const size_t UPL = (size_t)BCC * NN * MSTR * 2;    // 31,457,280 per U plane
    unsigned short* U_r = (unsigned short*)(rb);
    unsigned short* U_i = (unsigned short*)(rb + UPL);
    const size_t ADJ_F32 = (size_t)SKADJ * BCC * NN * NN * 8;   // 52,428,800
    const size_t ADJ_B16 = ADJ_F32 / 2;                         // 26,214,400

    gen_A<<<dim3(96, 5), 256, 0, stream>>>(traj, Ax_r, Ax_i, AxT_r, AxT_i, AyT_r, AyT_i);
    conv_img<<<dim3(5, 5, BCC), 256, 0, stream>>>(inp, iT_r, iT_i);
    fwd_gemm<<<dim3(960), 256, 81920, stream>>>(iT_r, iT_i, Ax_r, Ax_i, AyT_r, AyT_i, partial1);
    reduce_ksp<<<dim3(24, BCC), 256, 0, stream>>>(partial1, ksp);

    size_t total = (size_t)BCC * NN * NN;
    int rblocks = (int)((total + 255) / 256);

    if (ws_size >= BASE + 2 * UPL + ADJ_B16) {         // 105.2 MB — preferred (bf16 partials)
        void* partial2 = (void*)(rb + 2 * UPL);
        gen_U<<<dim3(3, NN, BCC), 256, 0, stream>>>(AyT_r, AyT_i, ksp, U_r, U_i);
        adj_gemm_pre<0><<<dim3(NADJB), 256, 0, stream>>>(AxT_r, AxT_i, U_r, U_i, partial2);
        reduce_out<0><<<rblocks, 256, 0, stream>>>(partial2, (float2*)d_out);
    } else if (ws_size >= BASE + ADJ_F32) {
        void* partial2 = (void*)rb;
        adj_gemm_fb<1><<<dim3(NADJB), 256, 0, stream>>>(AxT_r, AxT_i, AyT_r, AyT_i, ksp, partial2);
        reduce_out<1><<<rblocks, 256, 0, stream>>>(partial2, (float2*)d_out);
    } else {
        void* partial2 = (void*)rb;
        adj_gemm_fb<0><<<dim3(NADJB), 256, 0, stream>>>(AxT_r, AxT_i, AyT_r, AyT_i, ksp, partial2);
        reduce_out<0><<<rblocks, 256, 0, stream>>>(partial2, (float2*)d_out);
    }
}

// Round 16
// 130.381 us; speedup vs baseline: 1.1577x; 1.1577x over previous
//
#include <hip/hip_runtime.h>
#include <math.h>

// NUFFT roundtrip on bf16 MFMA (16x16x32), fp32 accumulate.
// R16 = R12 with fwd_gemm re-tiled to ADJ'S PROVEN CONFIG: 64y x 64m tile,
//   32KB LDS, 4 blocks/CU, wave-tile 32x32, grid 3840 (XCD-swizzled).
//   Evidence: R12's adj does the SAME 4.0e10 FLOP as fwd in ~39us vs fwd's
//   61.5us with the identical staging structure -- only the tile/residency
//   differ. Everything else is R12 verbatim (proven 132us).

#define NN      320
#define BCC     8
#define MREAL   6008
#define MSTR    6144
#define P1STR   6016
#define SKADJ   8
#define CHUNKM  (MSTR / SKADJ)      // 768
#define NADJB   (SKADJ * BCC * 25)  // 1600
#define NFWDB   (96 * 5 * BCC)      // 3840 fwd blocks (96 mt x 5 yt x 8 bc)
#define TWOPI   6.283185307179586f

typedef __attribute__((ext_vector_type(8))) short short8_t;
typedef __attribute__((ext_vector_type(4))) float float4_t;

__device__ __forceinline__ unsigned short f2bf(float f) {
    union { float f; unsigned u; } v; v.f = f;
    unsigned r = v.u + 0x7fff + ((v.u >> 16) & 1);
    return (unsigned short)(r >> 16);
}
__device__ __forceinline__ float bf2f(unsigned short h) {
    union { unsigned u; float f; } v; v.u = ((unsigned)h) << 16;
    return v.f;
}
__device__ __forceinline__ short8_t neg8(short8_t v) {
    short8_t r;
    #pragma unroll
    for (int i = 0; i < 8; ++i) r[i] = v[i] ^ (short)0x8000;
    return r;
}
__device__ __forceinline__ float gval(int i) { return (float)(i - NN/2); }

__device__ __forceinline__ void phase_cs(float k, float g, float* c, float* s) {
    float rev = k * (g * (1.0f / (float)NN));
    rev -= rintf(rev);
    float th = rev * TWOPI;
    __sincosf(th, s, c);
}

// async global -> LDS, 16B/lane, offset 0 (R11 lesson: imm offset moves LDS dest too)
__device__ __forceinline__ void gld16(const unsigned short* g, unsigned short* l) {
    __builtin_amdgcn_global_load_lds(
        (const __attribute__((address_space(1))) unsigned int*)g,
        (__attribute__((address_space(3))) unsigned int*)l, 16, 0, 0);
}

// ============ gen_A: Ax_sw[m][x], AxT_sw[x][m], AyT plain [y][m] ============
__global__ __launch_bounds__(256) void gen_A(
    const float* __restrict__ traj,
    unsigned short* __restrict__ Ax_r, unsigned short* __restrict__ Ax_i,
    unsigned short* __restrict__ AxT_r, unsigned short* __restrict__ AxT_i,
    unsigned short* __restrict__ AyT_r, unsigned short* __restrict__ AyT_i)
{
    __shared__ __align__(16) float lc[64][65];
    __shared__ __align__(16) float ls[64][65];
    __shared__ float kxv[64], kyv[64];
    const int tid = threadIdx.x;
    const int m0 = blockIdx.x * 64;
    const int g0 = blockIdx.y * 64;

    if (tid < 64) {
        int m = m0 + tid;
        kxv[tid] = (m < MREAL) ? traj[2*m]     : 0.f;
        kyv[tid] = (m < MREAL) ? traj[2*m + 1] : 0.f;
    }
    __syncthreads();

    #pragma unroll
    for (int it = 0; it < 16; ++it) {
        int e = tid + it * 256;
        int mi = e >> 6, gi = e & 63;
        float c, s;
        phase_cs(kxv[mi], gval(g0 + gi), &c, &s);
        bool valid = (m0 + mi) < MREAL;
        lc[mi][gi] = valid ? c : 0.f;
        ls[mi][gi] = valid ? s : 0.f;
    }
    __syncthreads();
    #pragma unroll
    for (int it = 0; it < 16; ++it) {   // Ax_sw[m][x0 + (xi ^ ((m&7)<<3))] = (c,-s)
        int e = tid + it * 256;
        int mi = e >> 6, xi = e & 63;
        int m = m0 + mi;
        size_t o = (size_t)m * NN + g0 + (xi ^ ((m & 7) << 3));
        Ax_r[o] = f2bf(lc[mi][xi]);
        Ax_i[o] = f2bf(-ls[mi][xi]);
    }
    #pragma unroll
    for (int it = 0; it < 16; ++it) {   // AxT_sw[x][m0 + (mi ^ ((x&7)<<3))] = (c,+s)
        int e = tid + it * 256;
        int xi = e >> 6, mi = e & 63;
        int x = g0 + xi;
        size_t o = (size_t)x * MSTR + m0 + (mi ^ ((x & 7) << 3));
        AxT_r[o] = f2bf(lc[mi][xi]);
        AxT_i[o] = f2bf(ls[mi][xi]);
    }
    __syncthreads();

    #pragma unroll
    for (int it = 0; it < 16; ++it) {
        int e = tid + it * 256;
        int mi = e >> 6, gi = e & 63;
        float c, s;
        phase_cs(kyv[mi], gval(g0 + gi), &c, &s);
        bool valid = (m0 + mi) < MREAL;
        lc[mi][gi] = valid ? c : 0.f;
        ls[mi][gi] = valid ? s : 0.f;
    }
    __syncthreads();
    #pragma unroll
    for (int it = 0; it < 16; ++it) {   // AyT[y][m] plain = (c,+s) = conj(Ay)
        int e = tid + it * 256;
        int yi = e >> 6, mi = e & 63;
        size_t o = (size_t)(g0 + yi) * MSTR + (m0 + mi);
        AyT_r[o] = f2bf(lc[mi][yi]);
        AyT_i[o] = f2bf(ls[mi][yi]);
    }
}

// ============ conv_img: inp float2 [bc][x][y] -> iT_sw bf16 [bc][y][x swz] ============
__global__ __launch_bounds__(256) void conv_img(
    const float* __restrict__ inp,
    unsigned short* __restrict__ iT_r, unsigned short* __restrict__ iT_i)
{
    __shared__ __align__(16) float2 t[64][65];
    const int tid = threadIdx.x;
    const int x0 = blockIdx.x * 64, y0 = blockIdx.y * 64, bc = blockIdx.z;
    const float2* ip = (const float2*)inp;
    #pragma unroll
    for (int it = 0; it < 16; ++it) {
        int e = tid + it * 256;
        int r = e >> 6, c = e & 63;
        t[r][c] = ip[((size_t)bc * NN + (x0 + r)) * NN + (y0 + c)];
    }
    __syncthreads();
    #pragma unroll
    for (int it = 0; it < 16; ++it) {
        int e = tid + it * 256;
        int yy = e >> 6, xx = e & 63;
        float2 v = t[xx][yy];
        int y = y0 + yy;
        size_t o = ((size_t)bc * NN + y) * NN + x0 + (xx ^ ((y & 7) << 3));
        iT_r[o] = f2bf(v.x);
        iT_i[o] = f2bf(v.y);
    }
}

// ---- shared 64x64 compute body (LDS: Ar[0,4K) Ai[4K,8K) Br[8K,12K) Bi[12K,16K))
__device__ __forceinline__ void ccompute(
    const unsigned short* ST, float4_t (&accR)[2][2], float4_t (&accI)[2][2],
    int kb, int sxor, int wa, int wb, int ar)
{
    #pragma unroll
    for (int ks = 0; ks < 2; ++ks) {
        const int e = (ks * 32 + kb * 8) ^ sxor;
        short8_t a_r[2], a_i[2], a_n[2], b_r[2], b_i[2];
        #pragma unroll
        for (int ix = 0; ix < 2; ++ix) {
            int rr = wa * 32 + ix * 16 + ar;
            a_r[ix] = *(const short8_t*)&ST[rr * 64 + e];
            a_i[ix] = *(const short8_t*)&ST[4096 + rr * 64 + e];
            a_n[ix] = neg8(a_i[ix]);
        }
        #pragma unroll
        for (int jy = 0; jy < 2; ++jy) {
            int cc = wb * 32 + jy * 16 + ar;
            b_r[jy] = *(const short8_t*)&ST[8192  + cc * 64 + e];
            b_i[jy] = *(const short8_t*)&ST[12288 + cc * 64 + e];
        }
        #pragma unroll
        for (int ix = 0; ix < 2; ++ix)
            #pragma unroll
            for (int jy = 0; jy < 2; ++jy) {
                accR[ix][jy] = __builtin_amdgcn_mfma_f32_16x16x32_bf16(a_r[ix], b_r[jy], accR[ix][jy], 0, 0, 0);
                accR[ix][jy] = __builtin_amdgcn_mfma_f32_16x16x32_bf16(a_n[ix], b_i[jy], accR[ix][jy], 0, 0, 0);
                accI[ix][jy] = __builtin_amdgcn_mfma_f32_16x16x32_bf16(a_r[ix], b_i[jy], accI[ix][jy], 0, 0, 0);
                accI[ix][jy] = __builtin_amdgcn_mfma_f32_16x16x32_bf16(a_i[ix], b_r[jy], accI[ix][jy], 0, 0, 0);
            }
    }
}

// ============ fwd_gemm: 64y x 64m tile (adj's proven config), BK=64 ============
__global__ __launch_bounds__(256) void fwd_gemm(
    const unsigned short* __restrict__ iT_r, const unsigned short* __restrict__ iT_i,
    const unsigned short* __restrict__ Ax_r, const unsigned short* __restrict__ Ax_i,
    const unsigned short* __restrict__ AyT_r, const unsigned short* __restrict__ AyT_i,
    float2* __restrict__ partial1)
{
    __shared__ __align__(16) unsigned short ST[16384];
    __shared__ __align__(16) float2 redbuf[2][64];

    const int tid = threadIdx.x;
    const int bid = blockIdx.x;
    const int nid = (bid & 7) * (NFWDB / 8) + (bid >> 3);
    const int mt  = nid / 40;                  // 0..95
    const int r40 = nid - mt * 40;
    const int yt  = r40 % 5;
    const int bc  = r40 / 5;
    const int m0  = mt * 64;
    const int y0  = yt * 64;

    float4_t accR[2][2], accI[2][2];
    #pragma unroll
    for (int i = 0; i < 2; ++i)
        #pragma unroll
        for (int j = 0; j < 2; ++j) { accR[i][j] = (float4_t)0.f; accI[i][j] = (float4_t)0.f; }

    const int lane = tid & 63, wid = tid >> 6;
    const int wy = wid & 1, wm = wid >> 1;     // waves: 2y x 2m, wave-tile 32x32
    const int ar = lane & 15, kb = lane >> 4;
    const int sxor = (lane & 7) << 3;

    const int lrow = lane >> 3;
    const int cb8  = (lane & 7) * 8;

    // staging addresses computed ONCE (8 issues/wave)
    const unsigned short* gp[8];
    unsigned short* lp[8];
    #pragma unroll
    for (int j = 0; j < 8; ++j) {
        int s = wid + 4 * j;                   // 0..31
        int row = (s & 7) * 8 + lrow;          // 0..63
        const unsigned short* g;
        if (s < 16) {                          // A: iT_sw rows y0..y0+63
            const unsigned short* pl = (s < 8) ? iT_r : iT_i;
            g = pl + ((size_t)bc * NN + (y0 + row)) * NN + cb8;
        } else {                               // B: Ax_sw rows m0..m0+63
            const unsigned short* pl = (s < 24) ? Ax_r : Ax_i;
            g = pl + (size_t)(m0 + row) * NN + cb8;
        }
        gp[j] = g;
        lp[j] = &ST[s * 512];
    }

    for (int t = 0; t < 5; ++t) {              // NN/64 x-tiles
        #pragma unroll
        for (int j = 0; j < 8; ++j) gld16(gp[j], lp[j]);
        #pragma unroll
        for (int j = 0; j < 8; ++j) gp[j] += 64;
        __syncthreads();                       // vmcnt drain -> tile ready
        ccompute(&ST[0], accR, accI, kb, sxor, wy, wm, ar);
        __syncthreads();
    }

    // epilogue: ksp partial = sum_y D[y][m]*Ay[m][y]; AyT plain stores (c,+s)
    #pragma unroll
    for (int jm = 0; jm < 2; ++jm) {
        float sr = 0.f, si = 0.f;
        int m = m0 + wm * 32 + jm * 16 + ar;
        #pragma unroll
        for (int iy = 0; iy < 2; ++iy)
            #pragma unroll
            for (int q = 0; q < 4; ++q) {
                int y = y0 + wy * 32 + iy * 16 + kb * 4 + q;
                float c  = bf2f(AyT_r[(size_t)y * MSTR + m]);
                float sy = bf2f(AyT_i[(size_t)y * MSTR + m]);
                float Tr = accR[iy][jm][q], Ti = accI[iy][jm][q];
                sr += Tr * c + Ti * sy;
                si += Ti * c - Tr * sy;
            }
        sr += __shfl_xor(sr, 16); sr += __shfl_xor(sr, 32);
        si += __shfl_xor(si, 16); si += __shfl_xor(si, 32);
        if ((lane & 48) == 0)
            redbuf[wy][wm * 32 + jm * 16 + ar] = make_float2(sr, si);
    }
    __syncthreads();
    if (tid < 64) {
        float2 a = redbuf[0][tid], b = redbuf[1][tid];
        int m = m0 + tid;
        if (m < MREAL)
            partial1[((size_t)bc * 5 + yt) * P1STR + m] = make_float2(a.x + b.x, a.y + b.y);
    }
}

// ============ reduce_ksp ============
__global__ void reduce_ksp(const float2* __restrict__ partial1,
                           float2* __restrict__ ksp)
{
    int mp = blockIdx.x * 256 + threadIdx.x;   // grid (24, 8)
    int bc = blockIdx.y;
    float2 r = make_float2(0.f, 0.f);
    if (mp < MREAL) {
        #pragma unroll
        for (int yt = 0; yt < 5; ++yt) {
            float2 v = partial1[((size_t)bc * 5 + yt) * P1STR + mp];
            r.x += v.x; r.y += v.y;
        }
    }
    ksp[(size_t)bc * MSTR + mp] = r;
}

// ============ gen_U: U_sw[bc][y][m ^ ((y&7)<<3)] = ksp[m]*conjAy[m][y] ============
__global__ __launch_bounds__(256) void gen_U(
    const unsigned short* __restrict__ AyT_r, const unsigned short* __restrict__ AyT_i,
    const float2* __restrict__ ksp,
    unsigned short* __restrict__ U_r, unsigned short* __restrict__ U_i)
{
    const int tid = threadIdx.x;
    const int m0 = blockIdx.x * 2048 + tid * 8;   // grid.x = 3
    const int y  = blockIdx.y;
    const int bc = blockIdx.z;

    short8_t yr = *(const short8_t*)(AyT_r + (size_t)y * MSTR + m0);
    short8_t yi = *(const short8_t*)(AyT_i + (size_t)y * MSTR + m0);
    const float2* kp = ksp + (size_t)bc * MSTR + m0;
    short8_t ur, ui;
    #pragma unroll
    for (int j = 0; j < 8; ++j) {
        float2 k = kp[j];
        float cr = bf2f((unsigned short)yr[j]);
        float ci = bf2f((unsigned short)yi[j]);
        ur[j] = (short)f2bf(k.x * cr - k.y * ci);
        ui[j] = (short)f2bf(k.x * ci + k.y * cr);
    }
    size_t o = ((size_t)bc * NN + y) * MSTR + (m0 ^ ((y & 7) << 3));
    *(short8_t*)(U_r + o) = ur;
    *(short8_t*)(U_i + o) = ui;
}

// ===== adj_gemm_pre: 64x x 64y, BK=64, split-K=8, single-buffered (R12) =====
template<int FP32P>
__global__ __launch_bounds__(256) void adj_gemm_pre(
    const unsigned short* __restrict__ AxT_r, const unsigned short* __restrict__ AxT_i,
    const unsigned short* __restrict__ U_r, const unsigned short* __restrict__ U_i,
    void* __restrict__ partial2)
{
    __shared__ __align__(16) unsigned short ST[16384];

    const int tid = threadIdx.x;
    const int bid = blockIdx.x;
    const int nid = (bid & 7) * (NADJB / 8) + (bid >> 3);
    const int bcsk = nid / 25;
    const int xy = nid - bcsk * 25;
    const int xt = xy / 5, yt = xy % 5;
    const int bc = bcsk % BCC, sk = bcsk / BCC;
    const int x0 = xt * 64, y0 = yt * 64;
    const int kbeg = sk * CHUNKM;

    float4_t accR[2][2], accI[2][2];
    #pragma unroll
    for (int i = 0; i < 2; ++i)
        #pragma unroll
        for (int j = 0; j < 2; ++j) { accR[i][j] = (float4_t)0.f; accI[i][j] = (float4_t)0.f; }

    const int lane = tid & 63, wid = tid >> 6;
    const int wx = wid >> 1, wyy = wid & 1;
    const int ar = lane & 15, kb = lane >> 4;
    const int sxor = (lane & 7) << 3;

    const int lrow = lane >> 3;
    const int cb8  = (lane & 7) * 8;

    // staging addresses computed ONCE (8 issues/wave)
    const unsigned short* gp[8];
    unsigned short* lp[8];
    #pragma unroll
    for (int j = 0; j < 8; ++j) {
        int s = wid + 4 * j;                   // 0..31
        int row = (s & 7) * 8 + lrow;          // 0..63
        const unsigned short* g;
        if (s < 16) {                          // A: AxT_sw rows x0..x0+63
            const unsigned short* pl = (s < 8) ? AxT_r : AxT_i;
            g = pl + (size_t)(x0 + row) * MSTR + kbeg + cb8;
        } else {                               // B: U_sw rows y0..y0+63
            const unsigned short* pl = (s < 24) ? U_r : U_i;
            g = pl + ((size_t)bc * NN + (y0 + row)) * MSTR + kbeg + cb8;
        }
        gp[j] = g;
        lp[j] = &ST[s * 512];
    }

    for (int t = 0; t < CHUNKM / 64; ++t) {    // 12 m-tiles
        #pragma unroll
        for (int j = 0; j < 8; ++j) gld16(gp[j], lp[j]);
        #pragma unroll
        for (int j = 0; j < 8; ++j) gp[j] += 64;
        __syncthreads();
        ccompute(&ST[0], accR, accI, kb, sxor, wx, wyy, ar);
        __syncthreads();
    }

    #pragma unroll
    for (int ix = 0; ix < 2; ++ix)
        #pragma unroll
        for (int jy = 0; jy < 2; ++jy)
            #pragma unroll
            for (int q = 0; q < 4; ++q) {
                int x = x0 + wx * 32 + ix * 16 + kb * 4 + q;
                int y = y0 + wyy * 32 + jy * 16 + ar;
                size_t o = (((size_t)sk * BCC + bc) * NN + x) * NN + y;
                float vr = accR[ix][jy][q], vi = accI[ix][jy][q];
                if (FP32P) {
                    ((float2*)partial2)[o] = make_float2(vr, vi);
                } else {
                    ((unsigned*)partial2)[o] =
                        (unsigned)f2bf(vr) | ((unsigned)f2bf(vi) << 16);
                }
            }
}

// ============ adj_gemm_fb: fallback (no U precompute, fused scale) ============
template<int FP32P>
__global__ __launch_bounds__(256) void adj_gemm_fb(
    const unsigned short* __restrict__ AxT_r, const unsigned short* __restrict__ AxT_i,
    const unsigned short* __restrict__ AyT_r, const unsigned short* __restrict__ AyT_i,
    const float2* __restrict__ ksp, void* __restrict__ partial2)
{
    __shared__ __align__(16) unsigned short Ar[64][72], Ai[64][72];
    __shared__ __align__(16) unsigned short Br[64][72], Bi[64][72];
    __shared__ __align__(16) float2 kspl[CHUNKM];

    const int tid = threadIdx.x;
    const int bid = blockIdx.x;
    const int nid = (bid & 7) * (NADJB / 8) + (bid >> 3);
    const int bcsk = nid / 25;
    const int xy = nid - bcsk * 25;
    const int xt = xy / 5, yt = xy % 5;
    const int bc = bcsk % BCC, sk = bcsk / BCC;
    const int x0 = xt * 64, y0 = yt * 64;
    const int kbeg = sk * CHUNKM;

    #pragma unroll
    for (int it = 0; it < CHUNKM / 256; ++it)
        kspl[tid + it * 256] = ksp[(size_t)bc * MSTR + kbeg + tid + it * 256];
    __syncthreads();

    float4_t accR[2][2], accI[2][2];
    #pragma unroll
    for (int i = 0; i < 2; ++i)
        #pragma unroll
        for (int j = 0; j < 2; ++j) { accR[i][j] = (float4_t)0.f; accI[i][j] = (float4_t)0.f; }

    const int lane = tid & 63, wid = tid >> 6;
    const int wx = wid >> 1, wyy = wid & 1;
    const int ar = lane & 15, kb = lane >> 4;
    const int sxor = (lane & 7) << 3;

    for (int mk = 0; mk < CHUNKM; mk += 64) {
        #pragma unroll
        for (int it = 0; it < 2; ++it) {
            int e = tid + it * 256;
            int row = e >> 3, gr = e & 7;
            size_t o = (size_t)(x0 + row) * MSTR + kbeg + mk + gr * 8;
            *(short8_t*)&Ar[row][gr * 8] = *(const short8_t*)(AxT_r + o);
            *(short8_t*)&Ai[row][gr * 8] = *(const short8_t*)(AxT_i + o);
        }
        #pragma unroll
        for (int it = 0; it < 2; ++it) {
            int e = tid + it * 256;
            int row = e >> 3, gr = e & 7;
            size_t o = (size_t)(y0 + row) * MSTR + kbeg + mk + gr * 8;
            short8_t yr = *(const short8_t*)(AyT_r + o);
            short8_t yi = *(const short8_t*)(AyT_i + o);
            short8_t br, bi2;
            #pragma unroll
            for (int j = 0; j < 8; ++j) {
                float2 k = kspl[mk + gr * 8 + j];
                float cr = bf2f((unsigned short)yr[j]);
                float ci = bf2f((unsigned short)yi[j]);
                br[j]  = (short)f2bf(k.x * cr - k.y * ci);
                bi2[j] = (short)f2bf(k.x * ci + k.y * cr);
            }
            *(short8_t*)&Br[row][gr * 8] = br;
            *(short8_t*)&Bi[row][gr * 8] = bi2;
        }
        __syncthreads();

        #pragma unroll
        for (int ks = 0; ks < 2; ++ks) {
            const int ea = (ks * 32 + kb * 8) ^ sxor;   // A content block-swizzled
            const int eb = ks * 32 + kb * 8;            // B staged plain
            short8_t a_r[2], a_i[2], a_n[2], b_r[2], b_i[2];
            #pragma unroll
            for (int ix = 0; ix < 2; ++ix) {
                int rr = wx * 32 + ix * 16 + ar;
                a_r[ix] = *(const short8_t*)&Ar[rr][ea];
                a_i[ix] = *(const short8_t*)&Ai[rr][ea];
                a_n[ix] = neg8(a_i[ix]);
            }
            #pragma unroll
            for (int jy = 0; jy < 2; ++jy) {
                int cc = wyy * 32 + jy * 16 + ar;
                b_r[jy] = *(const short8_t*)&Br[cc][eb];
                b_i[jy] = *(const short8_t*)&Bi[cc][eb];
            }
            #pragma unroll
            for (int ix = 0; ix < 2; ++ix)
                #pragma unroll
                for (int jy = 0; jy < 2; ++jy) {
                    accR[ix][jy] = __builtin_amdgcn_mfma_f32_16x16x32_bf16(a_r[ix], b_r[jy], accR[ix][jy], 0, 0, 0);
                    accR[ix][jy] = __builtin_amdgcn_mfma_f32_16x16x32_bf16(a_n[ix], b_i[jy], accR[ix][jy], 0, 0, 0);
                    accI[ix][jy] = __builtin_amdgcn_mfma_f32_16x16x32_bf16(a_r[ix], b_i[jy], accI[ix][jy], 0, 0, 0);
                    accI[ix][jy] = __builtin_amdgcn_mfma_f32_16x16x32_bf16(a_i[ix], b_r[jy], accI[ix][jy], 0, 0, 0);
                }
        }
        __syncthreads();
    }

    #pragma unroll
    for (int ix = 0; ix < 2; ++ix)
        #pragma unroll
        for (int jy = 0; jy < 2; ++jy)
            #pragma unroll
            for (int q = 0; q < 4; ++q) {
                int x = x0 + wx * 32 + ix * 16 + kb * 4 + q;
                int y = y0 + wyy * 32 + jy * 16 + ar;
                size_t o = (((size_t)sk * BCC + bc) * NN + x) * NN + y;
                float vr = accR[ix][jy][q], vi = accI[ix][jy][q];
                if (FP32P) {
                    ((float2*)partial2)[o] = make_float2(vr, vi);
                } else {
                    ((unsigned*)partial2)[o] =
                        (unsigned)f2bf(vr) | ((unsigned)f2bf(vi) << 16);
                }
            }
}

// ============ reduce_out ============
template<int FP32P>
__global__ void reduce_out(const void* __restrict__ partial2,
                           float2* __restrict__ out)
{
    size_t total = (size_t)BCC * NN * NN;
    size_t idx = (size_t)blockIdx.x * 256 + threadIdx.x;
    if (idx >= total) return;
    float2 r = make_float2(0.f, 0.f);
    #pragma unroll
    for (int s = 0; s < SKADJ; ++s) {
        if (FP32P) {
            float2 v = ((const float2*)partial2)[s * total + idx];
            r.x += v.x; r.y += v.y;
        } else {
            unsigned u = ((const unsigned*)partial2)[s * total + idx];
            r.x += bf2f((unsigned short)(u & 0xffff));
            r.y += bf2f((unsigned short)(u >> 16));
        }
    }
    out[idx] = r;
}

// ============ host ============
extern "C" void kernel_launch(void* const* d_in, const int* in_sizes, int n_in,
                              void* d_out, int out_size, void* d_ws, size_t ws_size,
                              hipStream_t stream)
{
    const float* inp  = (const float*)d_in[0];
    const float* traj = (const float*)d_in[1];

    char* ws = (char*)d_ws;
    const size_t PL = (size_t)NN * MSTR * 2;           // 3,932,160 B per bf16 plane
    unsigned short* AxT_r = (unsigned short*)(ws);
    unsigned short* AxT_i = (unsigned short*)(ws + PL);
    unsigned short* AyT_r = (unsigned short*)(ws + 2 * PL);
    unsigned short* AyT_i = (unsigned short*)(ws + 3 * PL);
    float2* ksp = (float2*)(ws + 4 * PL);
    const size_t KSPB = (size_t)BCC * MSTR * 8;        // 393,216
    const size_t BASE = 4 * PL + KSPB;                 // 16,121,856
    char* rb = ws + BASE;
    // fwd phase (dead after reduce_ksp; U / adj partials alias it):
    unsigned short* Ax_r = (unsigned short*)(rb);
    unsigned short* Ax_i = (unsigned short*)(rb + PL);
    const size_t ITP = (size_t)BCC * NN * NN * 2;      // 1,638,400 per plane
    unsigned short* iT_r = (unsigned short*)(rb + 2 * PL);
    unsigned short* iT_i = (unsigned short*)(rb + 2 * PL + ITP);
    float2* partial1 = (float2*)(rb + 2 * PL + 2 * ITP);
    // adj phase:
    const size_t UPL = (size_t)BCC * NN * MSTR * 2;    // 31,457,280 per U plane
    unsigned short* U_r = (unsigned short*)(rb);
    unsigned short* U_i = (unsigned short*)(rb + UPL);
    const size_t ADJ_F32 = (size_t)SKADJ * BCC * NN * NN * 8;   // 52,428,800
    const size_t ADJ_B16 = ADJ_F32 / 2;                         // 26,214,400

    gen_A<<<dim3(96, 5), 256, 0, stream>>>(traj, Ax_r, Ax_i, AxT_r, AxT_i, AyT_r, AyT_i);
    conv_img<<<dim3(5, 5, BCC), 256, 0, stream>>>(inp, iT_r, iT_i);
    fwd_gemm<<<dim3(NFWDB), 256, 0, stream>>>(iT_r, iT_i, Ax_r, Ax_i, AyT_r, AyT_i, partial1);
    reduce_ksp<<<dim3(24, BCC), 256, 0, stream>>>(partial1, ksp);

    size_t total = (size_t)BCC * NN * NN;
    int rblocks = (int)((total + 255) / 256);

    if (ws_size >= BASE + 2 * UPL + ADJ_B16) {         // 105.2 MB — preferred (bf16 partials)
        void* partial2 = (void*)(rb + 2 * UPL);
        gen_U<<<dim3(3, NN, BCC), 256, 0, stream>>>(AyT_r, AyT_i, ksp, U_r, U_i);
        adj_gemm_pre<0><<<dim3(NADJB), 256, 0, stream>>>(AxT_r, AxT_i, U_r, U_i, partial2);
        reduce_out<0><<<rblocks, 256, 0, stream>>>(partial2, (float2*)d_out);
    } else if (ws_size >= BASE + ADJ_F32) {
        void* partial2 = (void*)rb;
        adj_gemm_fb<1><<<dim3(NADJB), 256, 0, stream>>>(AxT_r, AxT_i, AyT_r, AyT_i, ksp, partial2);
        reduce_out<1><<<rblocks, 256, 0, stream>>>(partial2, (float2*)d_out);
    } else {
        void* partial2 = (void*)rb;
        adj_gemm_fb<0><<<dim3(NADJB), 256, 0, stream>>>(AxT_r, AxT_i, AyT_r, AyT_i, ksp, partial2);
        reduce_out<0><<<rblocks, 256, 0, stream>>>(partial2, (float2*)d_out);
    }
}